// Round 3
// baseline (817.583 us; speedup 1.0000x reference)
//
#include <hip/hip_runtime.h>

// Swin dilated-window cross-attention, MI355X bf16-MFMA, m97-style GEMMs.
// Phases: prep(weights T + rope) -> gemm_qvk (fused, +rope) -> attn -> gemm_proj(scatter)
// ws: Qbuf 64MB | Kbuf 64MB | Vbuf(T) 64MB | Obuf 64MB | qv_wt 1MB | k_wt .5 | proj_wt .5 | rope 16KB

typedef float v4f __attribute__((ext_vector_type(4)));
typedef short short8 __attribute__((ext_vector_type(8)));
typedef unsigned int v4u __attribute__((ext_vector_type(4)));

__device__ __forceinline__ unsigned short f2bf(float f) {
  unsigned int u = __builtin_bit_cast(unsigned int, f);
  u += 0x7fffu + ((u >> 16) & 1u);   // RNE
  return (unsigned short)(u >> 16);
}

__device__ __forceinline__ unsigned int pk_bf16(float a, float b) {
#if __has_builtin(__builtin_amdgcn_cvt_pk_bf16_f32)
  typedef __bf16 bf2 __attribute__((ext_vector_type(2)));
  bf2 r = __builtin_amdgcn_cvt_pk_bf16_f32(a, b);
  return __builtin_bit_cast(unsigned int, r);
#else
  return (unsigned int)f2bf(a) | ((unsigned int)f2bf(b) << 16);
#endif
}

// async global->LDS, 16B per lane, dest = wave-uniform base + lane*16
typedef const __attribute__((address_space(1))) void* gas_t;
typedef __attribute__((address_space(3))) void* las_t;
__device__ __forceinline__ void gll16(const void* g, void* l) {
  __builtin_amdgcn_global_load_lds((gas_t)(unsigned long long)g,
                                   (las_t)(unsigned int)(unsigned long long)l,
                                   16, 0, 0);
}

// token (g*64+n) -> pixel index (b*128+i)*128+j  (roll + window + dilation)
__device__ __forceinline__ int tok2pix(int tok) {
  int g = tok >> 6, n = tok & 63;
  int b = g >> 8, rem = g & 255;
  int d = rem & 3, bw = rem >> 2;
  int wh = bw >> 3, ww = bw & 7;
  int ph = n >> 3, pw = n & 7;
  int ii = (wh * 16 + 2 * ph + (d >> 1) + 4) & 127;
  int jj = (ww * 16 + 2 * pw + (d & 1) + 4) & 127;
  return (b * 128 + ii) * 128 + jj;
}

// ---------------- prep: weight transpose (64x64 LDS tiles) + rope tables ----------------
__global__ __launch_bounds__(256) void prep_kernel(
    const float* __restrict__ qv_w, const float* __restrict__ k_w,
    const float* __restrict__ proj_w,
    unsigned short* __restrict__ qv_wt, unsigned short* __restrict__ k_wt,
    unsigned short* __restrict__ proj_wt,
    float* __restrict__ rope_cos, float* __restrict__ rope_sin) {
  int id = blockIdx.x;
  int t = threadIdx.x;
  if (id < 256) {
    __shared__ unsigned short tile[64 * 72];
    const float* src;
    unsigned short* dst;
    int ldin, k0, c0;
    if (id < 128) {
      src = qv_w; dst = qv_wt; ldin = 1024;
      k0 = (id >> 4) * 64; c0 = (id & 15) * 64;
    } else if (id < 192) {
      int q = id - 128; src = k_w; dst = k_wt; ldin = 512;
      k0 = (q >> 3) * 64; c0 = (q & 7) * 64;
    } else {
      int q = id - 192; src = proj_w; dst = proj_wt; ldin = 512;
      k0 = (q >> 3) * 64; c0 = (q & 7) * 64;
    }
    int r = t >> 2, cq = t & 3;
    const float* p = src + (size_t)(k0 + r) * ldin + c0 + cq * 16;
    v4f f0 = *(const v4f*)(p + 0);
    v4f f1 = *(const v4f*)(p + 4);
    v4f f2 = *(const v4f*)(p + 8);
    v4f f3 = *(const v4f*)(p + 12);
    unsigned short* tr = tile + r * 72 + cq * 16;
    tr[0] = f2bf(f0[0]);  tr[1] = f2bf(f0[1]);  tr[2] = f2bf(f0[2]);  tr[3] = f2bf(f0[3]);
    tr[4] = f2bf(f1[0]);  tr[5] = f2bf(f1[1]);  tr[6] = f2bf(f1[2]);  tr[7] = f2bf(f1[3]);
    tr[8] = f2bf(f2[0]);  tr[9] = f2bf(f2[1]);  tr[10] = f2bf(f2[2]); tr[11] = f2bf(f2[3]);
    tr[12] = f2bf(f3[0]); tr[13] = f2bf(f3[1]); tr[14] = f2bf(f3[2]); tr[15] = f2bf(f3[3]);
    __syncthreads();
    int cr = t >> 2, kq = t & 3;   // out row c0+cr, k chunk kq
    union { unsigned short s[16]; short8 v[2]; } ob;
#pragma unroll
    for (int j = 0; j < 16; j++) ob.s[j] = tile[(kq * 16 + j) * 72 + cr];
    unsigned short* op = dst + (size_t)(c0 + cr) * 512 + k0 + kq * 16;
    *(short8*)(op) = ob.v[0];
    *(short8*)(op + 8) = ob.v[1];
  } else {
    // rope tables: idx = pos*32 + tt ; first 16 tt encode h, last 16 encode w
#pragma unroll
    for (int e = 0; e < 8; e++) {
      int idx = t * 8 + e;
      int pos = idx >> 5, tt = idx & 31;
      int ph = pos >> 3, pw = pos & 7;
      float ee = (float)(tt & 15) * (1.0f / 16.0f);
      float inv = powf(10000.0f, -ee);
      float ang = (float)(tt < 16 ? ph : pw) * inv;
      rope_cos[idx] = cosf(ang);
      rope_sin[idx] = sinf(ang);
    }
  }
}

// ---------------- fused qv + k GEMM (A fp32 gathered, B bf16 via DMA) ----------------
// grid (12, 512): bn<8 -> qv GEMM (N=1024), bn>=8 -> k GEMM (N=512)
__global__ __launch_bounds__(256) void gemm_qvk(
    const float* __restrict__ x, const float* __restrict__ cross,
    const unsigned short* __restrict__ qv_wt, const unsigned short* __restrict__ k_wt,
    const float* __restrict__ qv_b, const float* __restrict__ k_b,
    unsigned short* __restrict__ Qbuf, unsigned short* __restrict__ Kbuf,
    unsigned short* __restrict__ Vbuf,
    const float* __restrict__ rope_cos, const float* __restrict__ rope_sin) {
  __shared__ __attribute__((aligned(16))) unsigned short As[4096];  // [row][32] bf16, chunk^u swizzle
  __shared__ __attribute__((aligned(16))) unsigned short Bs[4096];  // [row][32] bf16 row-major
  const int tid = threadIdx.x;
  const int bn = blockIdx.x, bm = blockIdx.y;
  const bool isK = bn >= 8;
  const float* Asrc = isK ? cross : x;
  const unsigned short* Wt = isK ? k_wt : qv_wt;
  const int coln0 = (isK ? bn - 8 : bn) * 128;
  const int lane = tid & 63, w = tid >> 6;
  const int l15 = lane & 15, quad = lane >> 4;
  const int wm = (w & 1) * 64, wn = (w >> 1) * 64;
  char* AsB = (char*)As;
  char* BsB = (char*)Bs;

  // A staging: thread -> row ar = tid>>1, half ah = tid&1 (16 floats -> chunks 2ah,2ah+1)
  const int ar = tid >> 1, ah = tid & 1;
  const float* aptr = Asrc + (size_t)tok2pix(bm * 128 + ar) * 512 + ah * 16;
  const int au = (ar ^ (ar >> 2)) & 3;
  const int aoff0 = ar * 64 + (((ah * 2 + 0) ^ au) << 4);
  const int aoff1 = ar * 64 + (((ah * 2 + 1) ^ au) << 4);

  // B staging via DMA: 2 instrs/wave, rows w*32+s*16+(lane>>2), chunk lane&3
  const unsigned short* bptr[2];
  int boff[2];
#pragma unroll
  for (int s = 0; s < 2; s++) {
    int rl = w * 32 + s * 16 + (lane >> 2);
    bptr[s] = Wt + (size_t)(coln0 + rl) * 512 + (lane & 3) * 8;
    boff[s] = (w * 32 + s * 16) * 64;
  }

  v4f acc[4][4];
#pragma unroll
  for (int i = 0; i < 4; i++)
#pragma unroll
    for (int j = 0; j < 4; j++) acc[i][j] = (v4f){0.f, 0.f, 0.f, 0.f};

  for (int k0 = 0; k0 < 512; k0 += 32) {
    gll16(bptr[0], BsB + boff[0]);
    gll16(bptr[1], BsB + boff[1]);
    bptr[0] += 32;
    bptr[1] += 32;
    v4f a0 = *(const v4f*)(aptr + 0);
    v4f a1 = *(const v4f*)(aptr + 4);
    v4f a2 = *(const v4f*)(aptr + 8);
    v4f a3 = *(const v4f*)(aptr + 12);
    aptr += 32;
    v4u c0 = (v4u){pk_bf16(a0[0], a0[1]), pk_bf16(a0[2], a0[3]),
                   pk_bf16(a1[0], a1[1]), pk_bf16(a1[2], a1[3])};
    v4u c1 = (v4u){pk_bf16(a2[0], a2[1]), pk_bf16(a2[2], a2[3]),
                   pk_bf16(a3[0], a3[1]), pk_bf16(a3[2], a3[3])};
    *(v4u*)(AsB + aoff0) = c0;
    *(v4u*)(AsB + aoff1) = c1;
    __syncthreads();
    short8 af[4], bfr[4];
#pragma unroll
    for (int i = 0; i < 4; i++) {
      int r = wm + i * 16 + l15;
      int u = (r ^ (r >> 2)) & 3;
      af[i] = *(const short8*)(AsB + r * 64 + ((quad ^ u) << 4));
    }
#pragma unroll
    for (int j = 0; j < 4; j++)
      bfr[j] = *(const short8*)(BsB + (wn + j * 16 + l15) * 64 + (quad << 4));
#pragma unroll
    for (int i = 0; i < 4; i++)
#pragma unroll
      for (int j = 0; j < 4; j++)
        acc[i][j] = __builtin_amdgcn_mfma_f32_16x16x32_bf16(af[i], bfr[j], acc[i][j], 0, 0, 0);
    __syncthreads();
  }

  // Epilogue: C row = quad*4+r (token), col = l15 (+tiles). RoPE pair = col^1 = lane^1.
#pragma unroll
  for (int j = 0; j < 4; j++) {
    int col = coln0 + wn + j * 16 + l15;
    float bv = isK ? k_b[col] : qv_b[col];
#pragma unroll
    for (int i = 0; i < 4; i++) {
#pragma unroll
      for (int r = 0; r < 4; r++) {
        int tok = bm * 128 + wm + i * 16 + quad * 4 + r;
        float val = acc[i][j][r] + bv;
        int g = tok >> 6, n = tok & 63;
        int hh = (col >> 6) & 7, hd = col & 63;
        float part = __shfl_xor(val, 1);
        if (!isK && (col >> 9)) {            // V -> transposed [g][h][hd][n]
          Vbuf[(((g * 8 + hh) * 64 + hd) << 6) + n] = f2bf(val);
        } else {
          int ti = (n << 5) + (hd >> 1);
          float c = rope_cos[ti], s = rope_sin[ti];
          float o = (hd & 1) ? (part * s + val * c) : (val * c - part * s);
          if (!isK) {
            o *= 0.125f;                     // HD^-0.5
            Qbuf[(((g * 8 + hh) * 64 + n) << 6) + hd] = f2bf(o);
          } else {
            Kbuf[(((g * 8 + hh) * 64 + n) << 6) + hd] = f2bf(o);
          }
        }
      }
    }
  }
}

// ---------------- attention: one block per (g, head) ----------------
__global__ __launch_bounds__(256) void attn_kernel(
    const unsigned short* __restrict__ Qbuf, const unsigned short* __restrict__ Kbuf,
    const unsigned short* __restrict__ Vbuf, unsigned short* __restrict__ Obuf) {
  __shared__ __attribute__((aligned(16))) unsigned short Ps[4096];
  int bid = blockIdx.x;
  int g = bid >> 3, h = bid & 7;
  int tid = threadIdx.x;
  int lane = tid & 63, w = tid >> 6;
  int l15 = lane & 15, quad = lane >> 4;
  size_t base = ((size_t)(g * 8 + h)) << 12;
  const unsigned short* Q = Qbuf + base;
  const unsigned short* K = Kbuf + base;
  const unsigned short* Vt = Vbuf + base;

  v4f s[4];
#pragma unroll
  for (int j = 0; j < 4; j++) s[j] = (v4f){0.f, 0.f, 0.f, 0.f};
#pragma unroll
  for (int ki = 0; ki < 2; ki++) {
    short8 aq = *(const short8*)(Q + (w * 16 + l15) * 64 + ki * 32 + quad * 8);
#pragma unroll
    for (int j = 0; j < 4; j++) {
      short8 bk = *(const short8*)(K + (j * 16 + l15) * 64 + ki * 32 + quad * 8);
      s[j] = __builtin_amdgcn_mfma_f32_16x16x32_bf16(aq, bk, s[j], 0, 0, 0);
    }
  }

  int rem = g & 255;
  bool masked_win = ((rem >> 5) == 7);
  float p[4][4];
#pragma unroll
  for (int j = 0; j < 4; j++) {
    int m = j * 16 + l15;
    int pm = m >> 3;
    int gm = (int)(pm >= 4) + (int)(pm >= 6);
#pragma unroll
    for (int r = 0; r < 4; r++) {
      int row = w * 16 + quad * 4 + r;
      int pq = row >> 3;
      int gq = (int)(pq >= 4) + (int)(pq >= 6);
      float v = s[j][r];
      if (masked_win && gm != gq) v = -1e9f;
      p[j][r] = v;
    }
  }
#pragma unroll
  for (int r = 0; r < 4; r++) {
    float mx = fmaxf(fmaxf(p[0][r], p[1][r]), fmaxf(p[2][r], p[3][r]));
    mx = fmaxf(mx, __shfl_xor(mx, 1));
    mx = fmaxf(mx, __shfl_xor(mx, 2));
    mx = fmaxf(mx, __shfl_xor(mx, 4));
    mx = fmaxf(mx, __shfl_xor(mx, 8));
    float sum = 0.f;
#pragma unroll
    for (int j = 0; j < 4; j++) { p[j][r] = __expf(p[j][r] - mx); sum += p[j][r]; }
    sum += __shfl_xor(sum, 1);
    sum += __shfl_xor(sum, 2);
    sum += __shfl_xor(sum, 4);
    sum += __shfl_xor(sum, 8);
    float inv = 1.0f / sum;
    int row = w * 16 + quad * 4 + r;
#pragma unroll
    for (int j = 0; j < 4; j++) {
      int m = j * 16 + l15;
      int h8 = m >> 3;
      Ps[((h8 * 64 + (row ^ h8)) << 3) + (m & 7)] = f2bf(p[j][r] * inv);
    }
  }
  __syncthreads();

  v4f o[4];
#pragma unroll
  for (int j = 0; j < 4; j++) o[j] = (v4f){0.f, 0.f, 0.f, 0.f};
#pragma unroll
  for (int ki = 0; ki < 2; ki++) {
    int h8 = ki * 4 + quad;
    short8 ap = *(const short8*)(Ps + ((h8 * 64 + ((w * 16 + l15) ^ h8)) << 3));
#pragma unroll
    for (int j = 0; j < 4; j++) {
      short8 bv = *(const short8*)(Vt + (j * 16 + l15) * 64 + ki * 32 + quad * 8);
      o[j] = __builtin_amdgcn_mfma_f32_16x16x32_bf16(ap, bv, o[j], 0, 0, 0);
    }
  }
#pragma unroll
  for (int j = 0; j < 4; j++) {
    int hd = j * 16 + l15;
#pragma unroll
    for (int r = 0; r < 4; r++) {
      int row = w * 16 + quad * 4 + r;
      Obuf[(size_t)(g * 64 + row) * 512 + h * 64 + hd] = f2bf(o[j][r]);
    }
  }
}

// ---------------- proj GEMM (A bf16 token-order via DMA) + scatter ----------------
__global__ __launch_bounds__(256) void gemm_proj(
    const unsigned short* __restrict__ Obuf, const unsigned short* __restrict__ proj_wt,
    const float* __restrict__ proj_b, float* __restrict__ out) {
  __shared__ __attribute__((aligned(16))) unsigned short As[4096];
  __shared__ __attribute__((aligned(16))) unsigned short Bs[4096];
  const int tid = threadIdx.x;
  const int bn = blockIdx.x, bm = blockIdx.y;
  const int coln0 = bn * 128;
  const int lane = tid & 63, w = tid >> 6;
  const int l15 = lane & 15, quad = lane >> 4;
  const int wm = (w & 1) * 64, wn = (w >> 1) * 64;
  char* AsB = (char*)As;
  char* BsB = (char*)Bs;

  const unsigned short* aptr[2];
  const unsigned short* bptr[2];
  int soff[2];
#pragma unroll
  for (int s = 0; s < 2; s++) {
    int rl = w * 32 + s * 16 + (lane >> 2);
    aptr[s] = Obuf + (size_t)(bm * 128 + rl) * 512 + (lane & 3) * 8;
    bptr[s] = proj_wt + (size_t)(coln0 + rl) * 512 + (lane & 3) * 8;
    soff[s] = (w * 32 + s * 16) * 64;
  }

  v4f acc[4][4];
#pragma unroll
  for (int i = 0; i < 4; i++)
#pragma unroll
    for (int j = 0; j < 4; j++) acc[i][j] = (v4f){0.f, 0.f, 0.f, 0.f};

  for (int k0 = 0; k0 < 512; k0 += 32) {
#pragma unroll
    for (int s = 0; s < 2; s++) {
      gll16(aptr[s], AsB + soff[s]);
      gll16(bptr[s], BsB + soff[s]);
      aptr[s] += 32;
      bptr[s] += 32;
    }
    __syncthreads();
    short8 af[4], bfr[4];
#pragma unroll
    for (int i = 0; i < 4; i++)
      af[i] = *(const short8*)(AsB + (wm + i * 16 + l15) * 64 + (quad << 4));
#pragma unroll
    for (int j = 0; j < 4; j++)
      bfr[j] = *(const short8*)(BsB + (wn + j * 16 + l15) * 64 + (quad << 4));
#pragma unroll
    for (int i = 0; i < 4; i++)
#pragma unroll
      for (int j = 0; j < 4; j++)
        acc[i][j] = __builtin_amdgcn_mfma_f32_16x16x32_bf16(af[i], bfr[j], acc[i][j], 0, 0, 0);
    __syncthreads();
  }

  int pixr[4][4];
#pragma unroll
  for (int i = 0; i < 4; i++)
#pragma unroll
    for (int r = 0; r < 4; r++)
      pixr[i][r] = tok2pix(bm * 128 + wm + i * 16 + quad * 4 + r);
#pragma unroll
  for (int j = 0; j < 4; j++) {
    int col = coln0 + wn + j * 16 + l15;
    float bv = proj_b[col];
#pragma unroll
    for (int i = 0; i < 4; i++)
#pragma unroll
      for (int r = 0; r < 4; r++)
        out[(size_t)pixr[i][r] * 512 + col] = acc[i][j][r] + bv;
  }
}

extern "C" void kernel_launch(void* const* d_in, const int* in_sizes, int n_in,
                              void* d_out, int out_size, void* d_ws, size_t ws_size,
                              hipStream_t stream) {
  const float* x      = (const float*)d_in[0];
  const float* cross  = (const float*)d_in[1];
  const float* qv_w   = (const float*)d_in[2];
  const float* qv_b   = (const float*)d_in[3];
  const float* k_w    = (const float*)d_in[4];
  const float* k_b    = (const float*)d_in[5];
  const float* proj_w = (const float*)d_in[6];
  const float* proj_b = (const float*)d_in[7];

  char* ws = (char*)d_ws;
  const size_t MB = 1024 * 1024;
  unsigned short* Qbuf = (unsigned short*)(ws);
  unsigned short* Kbuf = (unsigned short*)(ws + 64 * MB);
  unsigned short* Vbuf = (unsigned short*)(ws + 128 * MB);
  unsigned short* Obuf = (unsigned short*)(ws + 192 * MB);
  unsigned short* qv_wt = (unsigned short*)(ws + 256 * MB);
  unsigned short* k_wt = qv_wt + 1024 * 512;
  unsigned short* proj_wt = k_wt + 512 * 512;
  float* rope_cos = (float*)(proj_wt + 512 * 512);
  float* rope_sin = rope_cos + 2048;

  prep_kernel<<<257, 256, 0, stream>>>(qv_w, k_w, proj_w, qv_wt, k_wt, proj_wt,
                                       rope_cos, rope_sin);
  gemm_qvk<<<dim3(12, 512), 256, 0, stream>>>(x, cross, qv_wt, k_wt, qv_b, k_b,
                                              Qbuf, Kbuf, Vbuf, rope_cos, rope_sin);
  attn_kernel<<<8192, 256, 0, stream>>>(Qbuf, Kbuf, Vbuf, Obuf);
  gemm_proj<<<dim3(4, 512), 256, 0, stream>>>(Obuf, proj_wt, proj_b, (float*)d_out);
}